// Round 1
// baseline (831.814 us; speedup 1.0000x reference)
//
#include <hip/hip_runtime.h>

typedef unsigned short u16;
typedef short short8 __attribute__((ext_vector_type(8)));
typedef float f32x4 __attribute__((ext_vector_type(4)));
typedef u16 us4 __attribute__((ext_vector_type(4)));

#define DIM   1536
#define NH    12
#define HD    128
#define SQ_   2640
#define SPAD  2688
#define PAST_ 10560
#define LTOT  13200
#define LPAD  13248

__device__ __forceinline__ u16 f2bf(float f){
  unsigned u = __builtin_bit_cast(unsigned, f);
  u += 0x7fffu + ((u >> 16) & 1u);
  return (u16)(u >> 16);
}
__device__ __forceinline__ float bf2f(u16 h){
  unsigned u = ((unsigned)h) << 16;
  return __builtin_bit_cast(float, u);
}
__device__ __forceinline__ void gload_lds16(const void* g, void* l){
  __builtin_amdgcn_global_load_lds(
      (const __attribute__((address_space(1))) void*)g,
      (__attribute__((address_space(3))) void*)l, 16, 0, 0);
}

// ---------------- prep kernels ----------------
__global__ void k_cvt(const float* __restrict__ s, u16* __restrict__ d, int n4){
  int i = blockIdx.x * 256 + threadIdx.x;
  if (i < n4){
    float4 f = ((const float4*)s)[i];
    us4 u; u[0]=f2bf(f.x); u[1]=f2bf(f.y); u[2]=f2bf(f.z); u[3]=f2bf(f.w);
    ((us4*)d)[i] = u;
  }
}

// x (2640x1536 f32) -> AB (2688x1536 bf16), pad rows zeroed
__global__ void k_prep_x(const float* __restrict__ x, u16* __restrict__ AB){
  int i = blockIdx.x * 256 + threadIdx.x;   // exactly 2688*1536/4 threads
  int e = i * 4;
  us4 u; u[0]=0; u[1]=0; u[2]=0; u[3]=0;
  if (e < SQ_*DIM){
    float4 f = ((const float4*)x)[i];
    u[0]=f2bf(f.x); u[1]=f2bf(f.y); u[2]=f2bf(f.z); u[3]=f2bf(f.w);
  }
  ((us4*)AB)[i] = u;
}

// cached (10560x1536 f32) -> dst rows [0,10560); zero rows [13200,13248)
__global__ void k_prep_cache(const float* __restrict__ src, u16* __restrict__ dst, int n4){
  int i = blockIdx.x * 256 + threadIdx.x;
  if (i >= n4) return;
  int e = i * 4;
  if (e < PAST_*DIM){
    float4 f = ((const float4*)src)[i];
    us4 u; u[0]=f2bf(f.x); u[1]=f2bf(f.y); u[2]=f2bf(f.z); u[3]=f2bf(f.w);
    ((us4*)dst)[i] = u;
  } else {
    us4 u; u[0]=0; u[1]=0; u[2]=0; u[3]=0;
    ((us4*)dst)[i - PAST_*DIM/4 + LTOT*DIM/4] = u;
  }
}

__global__ void k_zero(u16* __restrict__ d, int n4){
  int i = blockIdx.x * 256 + threadIdx.x;
  if (i < n4){ us4 u; u[0]=0; u[1]=0; u[2]=0; u[3]=0; ((us4*)d)[i] = u; }
}

// ---------------- fused QKV GEMM ----------------
// C[m,n] = sum_k A[m,k]*W[n,k] + b[n];  A: 2688x1536 bf16, W: 1536x1536 bf16
// n-tiles 0-11 -> Wq, 12-23 -> Wk, 24-35 -> Wv.
__global__ __launch_bounds__(256) void gemm_qkv(
  const u16* __restrict__ A,
  const u16* __restrict__ W0, const u16* __restrict__ W1, const u16* __restrict__ W2,
  const float* __restrict__ b0, const float* __restrict__ b1, const float* __restrict__ b2,
  u16* __restrict__ QL, u16* __restrict__ KL, u16* __restrict__ VA)
{
  __shared__ __align__(16) u16 As[4096];
  __shared__ __align__(16) u16 Bs[4096];
  int mt = blockIdx.x, nt = blockIdx.y;
  int tid = threadIdx.x, lane = tid & 63, w = tid >> 6;
  int wr = w >> 1, wc = w & 1;
  int which = nt / 12;
  const u16*  Bp = which==0 ? W0 : (which==1 ? W1 : W2);
  const float* bp = which==0 ? b0 : (which==1 ? b1 : b2);
  int nloc = (nt % 12) * 128;
  f32x4 acc[4][4];
  #pragma unroll
  for (int i=0;i<4;i++)
    #pragma unroll
    for (int j=0;j<4;j++) acc[i][j] = (f32x4){0.f,0.f,0.f,0.f};

  for (int k0 = 0; k0 < DIM; k0 += 32){
    #pragma unroll
    for (int p=0;p<2;p++){
      int e = (p*256 + tid) * 8;
      int r = e >> 5, c = e & 31;
      gload_lds16(A  + (size_t)(mt*128 + r)*DIM + k0 + c, (char*)As + p*4096 + (w<<10));
      gload_lds16(Bp + (size_t)(nloc   + r)*DIM + k0 + c, (char*)Bs + p*4096 + (w<<10));
    }
    __syncthreads();
    short8 af[4], bfr[4];
    #pragma unroll
    for (int i=0;i<4;i++){
      af[i]  = *(const short8*)&As[(wr*64 + i*16 + (lane&15))*32 + (lane>>4)*8];
      bfr[i] = *(const short8*)&Bs[(wc*64 + i*16 + (lane&15))*32 + (lane>>4)*8];
    }
    #pragma unroll
    for (int i=0;i<4;i++)
      #pragma unroll
      for (int j=0;j<4;j++)
        acc[i][j] = __builtin_amdgcn_mfma_f32_16x16x32_bf16(af[i], bfr[j], acc[i][j], 0,0,0);
    __syncthreads();
  }
  int rbase = mt*128 + wr*64;
  int cbase = nloc + wc*64;
  #pragma unroll
  for (int j=0;j<4;j++){
    int col = cbase + j*16 + (lane&15);
    float bb = bp[col];
    #pragma unroll
    for (int i=0;i<4;i++){
      #pragma unroll
      for (int q=0;q<4;q++){
        int row = rbase + i*16 + (lane>>4)*4 + q;
        if (row < SQ_){
          u16 uv = f2bf(acc[i][j][q] + bb);
          if (which==0)      QL[(size_t)row*DIM + col] = uv;
          else if (which==1) KL[(size_t)row*DIM + col] = uv;
          else               VA[(size_t)(PAST_ + row)*DIM + col] = uv;
        }
      }
    }
  }
}

// ---------------- output GEMM ----------------
__global__ __launch_bounds__(256) void gemm_out(
  const u16* __restrict__ A, const u16* __restrict__ W,
  const float* __restrict__ bias, float* __restrict__ out)
{
  __shared__ __align__(16) u16 As[4096];
  __shared__ __align__(16) u16 Bs[4096];
  int mt = blockIdx.x, nt = blockIdx.y;
  int tid = threadIdx.x, lane = tid & 63, w = tid >> 6;
  int wr = w >> 1, wc = w & 1;
  int nloc = nt * 128;
  f32x4 acc[4][4];
  #pragma unroll
  for (int i=0;i<4;i++)
    #pragma unroll
    for (int j=0;j<4;j++) acc[i][j] = (f32x4){0.f,0.f,0.f,0.f};

  for (int k0 = 0; k0 < DIM; k0 += 32){
    #pragma unroll
    for (int p=0;p<2;p++){
      int e = (p*256 + tid) * 8;
      int r = e >> 5, c = e & 31;
      gload_lds16(A + (size_t)(mt*128 + r)*DIM + k0 + c, (char*)As + p*4096 + (w<<10));
      gload_lds16(W + (size_t)(nloc   + r)*DIM + k0 + c, (char*)Bs + p*4096 + (w<<10));
    }
    __syncthreads();
    short8 af[4], bfr[4];
    #pragma unroll
    for (int i=0;i<4;i++){
      af[i]  = *(const short8*)&As[(wr*64 + i*16 + (lane&15))*32 + (lane>>4)*8];
      bfr[i] = *(const short8*)&Bs[(wc*64 + i*16 + (lane&15))*32 + (lane>>4)*8];
    }
    #pragma unroll
    for (int i=0;i<4;i++)
      #pragma unroll
      for (int j=0;j<4;j++)
        acc[i][j] = __builtin_amdgcn_mfma_f32_16x16x32_bf16(af[i], bfr[j], acc[i][j], 0,0,0);
    __syncthreads();
  }
  int rbase = mt*128 + wr*64;
  int cbase = nloc + wc*64;
  #pragma unroll
  for (int j=0;j<4;j++){
    int col = cbase + j*16 + (lane&15);
    float bb = bias[col];
    #pragma unroll
    for (int i=0;i<4;i++){
      #pragma unroll
      for (int q=0;q<4;q++){
        int row = rbase + i*16 + (lane>>4)*4 + q;
        if (row < SQ_) out[(size_t)row*DIM + col] = acc[i][j][q] + bb;
      }
    }
  }
}

// ---------------- RMSNorm + RoPE ----------------
// grid (2640, 2): y==0 -> q (in-place on QL), y==1 -> k (KL -> K_all row PAST+s)
__global__ __launch_bounds__(256) void norm_rope(
  const u16* __restrict__ QL, const u16* __restrict__ KL,
  const float* __restrict__ freqs, const float* __restrict__ gq, const float* __restrict__ gk,
  const int* __restrict__ cs,
  u16* __restrict__ Qout, u16* __restrict__ KAout)
{
  int s = blockIdx.x;
  int isk = blockIdx.y;
  int tid = threadIdx.x;
  const u16* src = (isk ? KL : QL) + (size_t)s*DIM + tid*6;
  float y[6];
  #pragma unroll
  for (int t=0;t<6;t++) y[t] = bf2f(src[t]);
  float ss = 0.f;
  #pragma unroll
  for (int t=0;t<6;t++) ss += y[t]*y[t];
  for (int mk=1; mk<64; mk<<=1) ss += __shfl_xor(ss, mk);
  __shared__ float red[4];
  if ((tid & 63) == 0) red[tid>>6] = ss;
  __syncthreads();
  float rn = rsqrtf((red[0]+red[1]+red[2]+red[3]) * (1.0f/1536.0f) + 1e-6f);
  const float* g = (isk ? gk : gq) + tid*6;
  int pos = cs[0] + s;
  int tpos = pos / 880, rem = pos % 880;
  int hh = rem / 40, wp = rem % 40;
  u16 ov[6];
  #pragma unroll
  for (int pi=0; pi<3; pi++){
    int p = tid*3 + pi;
    int i = p & 63;
    int fr = (i < 22) ? tpos : ((i < 43) ? hh : wp);
    float ang = freqs[fr*64 + i];
    float sn, c;
    sincosf(ang, &sn, &c);
    float e  = y[pi*2]   * rn * g[pi*2];
    float od = y[pi*2+1] * rn * g[pi*2+1];
    ov[pi*2]   = f2bf(e*c - od*sn);
    ov[pi*2+1] = f2bf(od*c + e*sn);
  }
  u16* dst = isk ? (KAout + (size_t)(PAST_ + s)*DIM + tid*6)
                 : (Qout  + (size_t)s*DIM + tid*6);
  #pragma unroll
  for (int t=0;t<6;t++) dst[t] = ov[t];
}

// ---------------- flash attention ----------------
// block = (q-tile of 64 rows, head). 4 waves x 16 q-rows. KVB=64.
__global__ __launch_bounds__(256) void attn(
  const u16* __restrict__ Qf, const u16* __restrict__ KA,
  const u16* __restrict__ VA, u16* __restrict__ Out)
{
  __shared__ __align__(16) u16 Ks[64*128];   // [kv][d], XOR-swizzled rows
  __shared__ __align__(16) u16 Vt[128*64];   // [d][kv] transposed, XOR-swizzled
  __shared__ __align__(16) u16 Ps[4][16*80]; // per-wave P, row stride 80
  int h = blockIdx.y, qt = blockIdx.x;
  int tid = threadIdx.x, lane = tid & 63, w = tid >> 6;
  int qrow0 = qt*64 + w*16;
  short8 qa[4];
  {
    const u16* qb = Qf + (size_t)(qrow0 + (lane&15))*DIM + h*HD + (lane>>4)*8;
    #pragma unroll
    for (int kt=0;kt<4;kt++) qa[kt] = *(const short8*)(qb + kt*32);
  }
  f32x4 o[8];
  #pragma unroll
  for (int dt=0;dt<8;dt++) o[dt] = (f32x4){0.f,0.f,0.f,0.f};
  float m[4] = {-1e30f,-1e30f,-1e30f,-1e30f};
  float l[4] = {0.f,0.f,0.f,0.f};
  const float SC = 0.08838834764831845f * 1.4426950408889634f; // 1/sqrt(128) * log2(e)

  for (int kv0 = 0; kv0 < LPAD; kv0 += 64){
    // --- stage K via global_load_lds, source pre-swizzled (rule #21) ---
    #pragma unroll
    for (int p=0;p<4;p++){
      int e = w*2048 + p*512 + lane*8;
      int r = e >> 7;
      int bcol = (e & 127) << 1;             // byte col within 256B row
      int sb = bcol ^ ((r & 7) << 4);
      gload_lds16(KA + (size_t)(kv0 + r)*DIM + h*HD + (sb>>1),
                  (char*)Ks + w*4096 + p*1024);
    }
    // --- stage V transposed via registers ---
    {
      int c0 = (tid >> 4) << 3;   // d group 0..120
      int r0 = (tid & 15) << 2;   // kv group 0..60
      const u16* vs = VA + (size_t)(kv0 + r0)*DIM + h*HD + c0;
      short8 v0 = *(const short8*)(vs);
      short8 v1 = *(const short8*)(vs + DIM);
      short8 v2 = *(const short8*)(vs + 2*DIM);
      short8 v3 = *(const short8*)(vs + 3*DIM);
      #pragma unroll
      for (int j=0;j<8;j++){
        int d = c0 + j;
        int off = d*128 + ((r0*2) ^ ((d & 7) << 4));
        us4 pk; pk[0]=(u16)v0[j]; pk[1]=(u16)v1[j]; pk[2]=(u16)v2[j]; pk[3]=(u16)v3[j];
        *(us4*)((char*)Vt + off) = pk;
      }
    }
    __syncthreads();
    // --- QK^T ---
    f32x4 s4[4];
    #pragma unroll
    for (int ct=0;ct<4;ct++) s4[ct] = (f32x4){0.f,0.f,0.f,0.f};
    #pragma unroll
    for (int ct=0;ct<4;ct++){
      int row = ct*16 + (lane&15);
      int rbyte = row*256, sw = (row & 7) << 4;
      #pragma unroll
      for (int kt=0;kt<4;kt++){
        int b = (kt*64 + ((lane>>4)<<4)) ^ sw;
        short8 kb = *(const short8*)((const char*)Ks + rbyte + b);
        s4[ct] = __builtin_amdgcn_mfma_f32_16x16x32_bf16(qa[kt], kb, s4[ct], 0,0,0);
      }
    }
    // --- online softmax (exp2 domain) ---
    float xv[4][4];
    #pragma unroll
    for (int ct=0;ct<4;ct++)
      #pragma unroll
      for (int j=0;j<4;j++) xv[ct][j] = s4[ct][j] * SC;
    if (kv0 + 64 > LTOT){
      #pragma unroll
      for (int ct=0;ct<4;ct++){
        int col = kv0 + ct*16 + (lane&15);
        if (col >= LTOT){
          #pragma unroll
          for (int j=0;j<4;j++) xv[ct][j] = -1e30f;
        }
      }
    }
    float al[4];
    #pragma unroll
    for (int j=0;j<4;j++){
      float rm = fmaxf(fmaxf(xv[0][j],xv[1][j]), fmaxf(xv[2][j],xv[3][j]));
      rm = fmaxf(rm, __shfl_xor(rm, 1));
      rm = fmaxf(rm, __shfl_xor(rm, 2));
      rm = fmaxf(rm, __shfl_xor(rm, 4));
      rm = fmaxf(rm, __shfl_xor(rm, 8));
      float mn = fmaxf(m[j], rm);
      al[j] = exp2f(m[j] - mn);
      m[j] = mn;
    }
    #pragma unroll
    for (int ct=0;ct<4;ct++)
      #pragma unroll
      for (int j=0;j<4;j++) xv[ct][j] = exp2f(xv[ct][j] - m[j]);
    #pragma unroll
    for (int j=0;j<4;j++){
      float rs = xv[0][j]+xv[1][j]+xv[2][j]+xv[3][j];
      rs += __shfl_xor(rs, 1); rs += __shfl_xor(rs, 2);
      rs += __shfl_xor(rs, 4); rs += __shfl_xor(rs, 8);
      l[j] = l[j]*al[j] + rs;
    }
    #pragma unroll
    for (int dt=0;dt<8;dt++){
      f32x4 t = o[dt];
      t[0]*=al[0]; t[1]*=al[1]; t[2]*=al[2]; t[3]*=al[3];
      o[dt] = t;
    }
    // --- P -> LDS (bf16) -> A-frags ---
    u16* pw = &Ps[w][0];
    #pragma unroll
    for (int ct=0;ct<4;ct++)
      #pragma unroll
      for (int j=0;j<4;j++)
        pw[((lane>>4)*4 + j)*80 + ct*16 + (lane&15)] = f2bf(xv[ct][j]);
    short8 pa[2];
    #pragma unroll
    for (int kh=0;kh<2;kh++)
      pa[kh] = *(const short8*)&pw[(lane&15)*80 + kh*32 + (lane>>4)*8];
    // --- PV ---
    #pragma unroll
    for (int dt=0;dt<8;dt++){
      int row = dt*16 + (lane&15);
      int rbyte = row*128, sw = (row & 7) << 4;
      #pragma unroll
      for (int kh=0;kh<2;kh++){
        int b = (kh*64 + ((lane>>4)<<4)) ^ sw;
        short8 vb = *(const short8*)((const char*)Vt + rbyte + b);
        o[dt] = __builtin_amdgcn_mfma_f32_16x16x32_bf16(pa[kh], vb, o[dt], 0,0,0);
      }
    }
    __syncthreads();
  }
  #pragma unroll
  for (int j=0;j<4;j++) l[j] = 1.0f / l[j];
  #pragma unroll
  for (int dt=0;dt<8;dt++){
    #pragma unroll
    for (int j=0;j<4;j++){
      int row = qrow0 + (lane>>4)*4 + j;
      Out[(size_t)row*DIM + h*HD + dt*16 + (lane&15)] = f2bf(o[dt][j] * l[j]);
    }
  }
}

// ---------------- launch ----------------
extern "C" void kernel_launch(void* const* d_in, const int* in_sizes, int n_in,
                              void* d_out, int out_size, void* d_ws, size_t ws_size,
                              hipStream_t stream) {
  (void)in_sizes; (void)n_in; (void)out_size; (void)ws_size;
  const float* x    = (const float*)d_in[0];
  const float* freqs= (const float*)d_in[1];
  const float* ck   = (const float*)d_in[2];
  const float* cv   = (const float*)d_in[3];
  const float* Wq   = (const float*)d_in[4];
  const float* bq   = (const float*)d_in[5];
  const float* Wk   = (const float*)d_in[6];
  const float* bk   = (const float*)d_in[7];
  const float* Wv   = (const float*)d_in[8];
  const float* bv   = (const float*)d_in[9];
  const float* Wo   = (const float*)d_in[10];
  const float* bo   = (const float*)d_in[11];
  const float* gq   = (const float*)d_in[12];
  const float* gk   = (const float*)d_in[13];
  const int*   cs   = (const int*)d_in[14];
  float* out = (float*)d_out;
  char* ws = (char*)d_ws;

  u16* AB  = (u16*)(ws);               // 2688x1536 bf16: x_bf16, later attn_out
  u16* Wb0 = (u16*)(ws + 8257536);
  u16* Wb1 = (u16*)(ws + 12976128);
  u16* Wb2 = (u16*)(ws + 17694720);
  u16* Wb3 = (u16*)(ws + 22413312);
  u16* QL  = (u16*)(ws + 27131904);    // 2688x1536: q_lin -> (in-place) q roped
  u16* KL  = (u16*)(ws + 35389440);    // 2640x1536: k_lin
  u16* KA  = (u16*)(ws + 43499520);    // 13248x1536: K_all
  u16* VA  = (u16*)(ws + 84197376);    // 13248x1536: V_all

  k_cvt<<<2304, 256, 0, stream>>>(Wq, Wb0, 589824);
  k_cvt<<<2304, 256, 0, stream>>>(Wk, Wb1, 589824);
  k_cvt<<<2304, 256, 0, stream>>>(Wv, Wb2, 589824);
  k_cvt<<<2304, 256, 0, stream>>>(Wo, Wb3, 589824);
  k_prep_x<<<4032, 256, 0, stream>>>(x, AB);
  k_prep_cache<<<15912, 256, 0, stream>>>(ck, KA, 4073472);
  k_prep_cache<<<15912, 256, 0, stream>>>(cv, VA, 4073472);
  k_zero<<<72, 256, 0, stream>>>(QL + (size_t)SQ_*DIM, 18432);

  gemm_qkv<<<dim3(21,36), 256, 0, stream>>>(AB, Wb0, Wb1, Wb2, bq, bk, bv, QL, KL, VA);
  norm_rope<<<dim3(2640,2), 256, 0, stream>>>(QL, KL, freqs, gq, gk, cs, QL, KA);
  attn<<<dim3(42,12), 256, 0, stream>>>(QL, KA, VA, AB);
  gemm_out<<<dim3(21,12), 256, 0, stream>>>(AB, Wb3, bo, out);
}

// Round 5
// 779.631 us; speedup vs baseline: 1.0669x; 1.0669x over previous
//
#include <hip/hip_runtime.h>

typedef unsigned short u16;
typedef short short8 __attribute__((ext_vector_type(8)));
typedef float f32x4 __attribute__((ext_vector_type(4)));
typedef u16 us4 __attribute__((ext_vector_type(4)));

#define DIM   1536
#define NH    12
#define HD    128
#define SQ_   2640
#define SPAD  2688
#define PAST_ 10560
#define LTOT  13200
#define LPAD  13248

__device__ __forceinline__ u16 f2bf(float f){
  unsigned u = __builtin_bit_cast(unsigned, f);
  u += 0x7fffu + ((u >> 16) & 1u);
  return (u16)(u >> 16);
}
__device__ __forceinline__ float bf2f(u16 h){
  unsigned u = ((unsigned)h) << 16;
  return __builtin_bit_cast(float, u);
}
__device__ __forceinline__ void gload_lds16(const void* g, void* l){
  __builtin_amdgcn_global_load_lds(
      (const __attribute__((address_space(1))) void*)g,
      (__attribute__((address_space(3))) void*)l, 16, 0, 0);
}

// ---------------- prep kernels ----------------
__global__ void k_cvt(const float* __restrict__ s, u16* __restrict__ d, int n4){
  int i = blockIdx.x * 256 + threadIdx.x;
  if (i < n4){
    float4 f = ((const float4*)s)[i];
    us4 u; u[0]=f2bf(f.x); u[1]=f2bf(f.y); u[2]=f2bf(f.z); u[3]=f2bf(f.w);
    ((us4*)d)[i] = u;
  }
}

__global__ void k_prep_x(const float* __restrict__ x, u16* __restrict__ AB){
  int i = blockIdx.x * 256 + threadIdx.x;
  int e = i * 4;
  us4 u; u[0]=0; u[1]=0; u[2]=0; u[3]=0;
  if (e < SQ_*DIM){
    float4 f = ((const float4*)x)[i];
    u[0]=f2bf(f.x); u[1]=f2bf(f.y); u[2]=f2bf(f.z); u[3]=f2bf(f.w);
  }
  ((us4*)AB)[i] = u;
}

__global__ void k_prep_cache(const float* __restrict__ src, u16* __restrict__ dst, int n4){
  int i = blockIdx.x * 256 + threadIdx.x;
  if (i >= n4) return;
  int e = i * 4;
  if (e < PAST_*DIM){
    float4 f = ((const float4*)src)[i];
    us4 u; u[0]=f2bf(f.x); u[1]=f2bf(f.y); u[2]=f2bf(f.z); u[3]=f2bf(f.w);
    ((us4*)dst)[i] = u;
  } else {
    us4 u; u[0]=0; u[1]=0; u[2]=0; u[3]=0;
    ((us4*)dst)[i - PAST_*DIM/4 + LTOT*DIM/4] = u;
  }
}

__global__ void k_zero(u16* __restrict__ d, int n4){
  int i = blockIdx.x * 256 + threadIdx.x;
  if (i < n4){ us4 u; u[0]=0; u[1]=0; u[2]=0; u[3]=0; ((us4*)d)[i] = u; }
}

// ---------------- fused QKV GEMM ----------------
__global__ __launch_bounds__(256) void gemm_qkv(
  const u16* __restrict__ A,
  const u16* __restrict__ W0, const u16* __restrict__ W1, const u16* __restrict__ W2,
  const float* __restrict__ b0, const float* __restrict__ b1, const float* __restrict__ b2,
  u16* __restrict__ QL, u16* __restrict__ KL, u16* __restrict__ VA)
{
  __shared__ __align__(16) u16 As[4096];
  __shared__ __align__(16) u16 Bs[4096];
  int mt = blockIdx.x, nt = blockIdx.y;
  int tid = threadIdx.x, lane = tid & 63, w = tid >> 6;
  int wr = w >> 1, wc = w & 1;
  int which = nt / 12;
  const u16*  Bp = which==0 ? W0 : (which==1 ? W1 : W2);
  const float* bp = which==0 ? b0 : (which==1 ? b1 : b2);
  int nloc = (nt % 12) * 128;
  f32x4 acc[4][4];
  #pragma unroll
  for (int i=0;i<4;i++)
    #pragma unroll
    for (int j=0;j<4;j++) acc[i][j] = (f32x4){0.f,0.f,0.f,0.f};

  for (int k0 = 0; k0 < DIM; k0 += 32){
    #pragma unroll
    for (int p=0;p<2;p++){
      int e = (p*256 + tid) * 8;
      int r = e >> 5, c = e & 31;
      gload_lds16(A  + (size_t)(mt*128 + r)*DIM + k0 + c, (char*)As + p*4096 + (w<<10));
      gload_lds16(Bp + (size_t)(nloc   + r)*DIM + k0 + c, (char*)Bs + p*4096 + (w<<10));
    }
    __syncthreads();
    short8 af[4], bfr[4];
    #pragma unroll
    for (int i=0;i<4;i++){
      af[i]  = *(const short8*)&As[(wr*64 + i*16 + (lane&15))*32 + (lane>>4)*8];
      bfr[i] = *(const short8*)&Bs[(wc*64 + i*16 + (lane&15))*32 + (lane>>4)*8];
    }
    #pragma unroll
    for (int i=0;i<4;i++)
      #pragma unroll
      for (int j=0;j<4;j++)
        acc[i][j] = __builtin_amdgcn_mfma_f32_16x16x32_bf16(af[i], bfr[j], acc[i][j], 0,0,0);
    __syncthreads();
  }
  int rbase = mt*128 + wr*64;
  int cbase = nloc + wc*64;
  #pragma unroll
  for (int j=0;j<4;j++){
    int col = cbase + j*16 + (lane&15);
    float bb = bp[col];
    #pragma unroll
    for (int i=0;i<4;i++){
      #pragma unroll
      for (int q=0;q<4;q++){
        int row = rbase + i*16 + (lane>>4)*4 + q;
        if (row < SQ_){
          u16 uv = f2bf(acc[i][j][q] + bb);
          if (which==0)      QL[(size_t)row*DIM + col] = uv;
          else if (which==1) KL[(size_t)row*DIM + col] = uv;
          else               VA[(size_t)(PAST_ + row)*DIM + col] = uv;
        }
      }
    }
  }
}

// ---------------- output GEMM ----------------
__global__ __launch_bounds__(256) void gemm_out(
  const u16* __restrict__ A, const u16* __restrict__ W,
  const float* __restrict__ bias, float* __restrict__ out)
{
  __shared__ __align__(16) u16 As[4096];
  __shared__ __align__(16) u16 Bs[4096];
  int mt = blockIdx.x, nt = blockIdx.y;
  int tid = threadIdx.x, lane = tid & 63, w = tid >> 6;
  int wr = w >> 1, wc = w & 1;
  int nloc = nt * 128;
  f32x4 acc[4][4];
  #pragma unroll
  for (int i=0;i<4;i++)
    #pragma unroll
    for (int j=0;j<4;j++) acc[i][j] = (f32x4){0.f,0.f,0.f,0.f};

  for (int k0 = 0; k0 < DIM; k0 += 32){
    #pragma unroll
    for (int p=0;p<2;p++){
      int e = (p*256 + tid) * 8;
      int r = e >> 5, c = e & 31;
      gload_lds16(A + (size_t)(mt*128 + r)*DIM + k0 + c, (char*)As + p*4096 + (w<<10));
      gload_lds16(W + (size_t)(nloc   + r)*DIM + k0 + c, (char*)Bs + p*4096 + (w<<10));
    }
    __syncthreads();
    short8 af[4], bfr[4];
    #pragma unroll
    for (int i=0;i<4;i++){
      af[i]  = *(const short8*)&As[(wr*64 + i*16 + (lane&15))*32 + (lane>>4)*8];
      bfr[i] = *(const short8*)&Bs[(wc*64 + i*16 + (lane&15))*32 + (lane>>4)*8];
    }
    #pragma unroll
    for (int i=0;i<4;i++)
      #pragma unroll
      for (int j=0;j<4;j++)
        acc[i][j] = __builtin_amdgcn_mfma_f32_16x16x32_bf16(af[i], bfr[j], acc[i][j], 0,0,0);
    __syncthreads();
  }
  int rbase = mt*128 + wr*64;
  int cbase = nloc + wc*64;
  #pragma unroll
  for (int j=0;j<4;j++){
    int col = cbase + j*16 + (lane&15);
    float bb = bias[col];
    #pragma unroll
    for (int i=0;i<4;i++){
      #pragma unroll
      for (int q=0;q<4;q++){
        int row = rbase + i*16 + (lane>>4)*4 + q;
        if (row < SQ_) out[(size_t)row*DIM + col] = acc[i][j][q] + bb;
      }
    }
  }
}

// ---------------- RMSNorm + RoPE (r1 verbatim, no prescale) ----------------
__global__ __launch_bounds__(256) void norm_rope(
  const u16* __restrict__ QL, const u16* __restrict__ KL,
  const float* __restrict__ freqs, const float* __restrict__ gq, const float* __restrict__ gk,
  const int* __restrict__ cs,
  u16* __restrict__ Qout, u16* __restrict__ KAout)
{
  int s = blockIdx.x;
  int isk = blockIdx.y;
  int tid = threadIdx.x;
  const u16* src = (isk ? KL : QL) + (size_t)s*DIM + tid*6;
  float y[6];
  #pragma unroll
  for (int t=0;t<6;t++) y[t] = bf2f(src[t]);
  float ss = 0.f;
  #pragma unroll
  for (int t=0;t<6;t++) ss += y[t]*y[t];
  for (int mk=1; mk<64; mk<<=1) ss += __shfl_xor(ss, mk);
  __shared__ float red[4];
  if ((tid & 63) == 0) red[tid>>6] = ss;
  __syncthreads();
  float rn = rsqrtf((red[0]+red[1]+red[2]+red[3]) * (1.0f/1536.0f) + 1e-6f);
  const float* g = (isk ? gk : gq) + tid*6;
  int pos = cs[0] + s;
  int tpos = pos / 880, rem = pos % 880;
  int hh = rem / 40, wp = rem % 40;
  u16 ov[6];
  #pragma unroll
  for (int pi=0; pi<3; pi++){
    int p = tid*3 + pi;
    int i = p & 63;
    int fr = (i < 22) ? tpos : ((i < 43) ? hh : wp);
    float ang = freqs[fr*64 + i];
    float sn, c;
    sincosf(ang, &sn, &c);
    float e  = y[pi*2]   * rn * g[pi*2];
    float od = y[pi*2+1] * rn * g[pi*2+1];
    ov[pi*2]   = f2bf(e*c - od*sn);
    ov[pi*2+1] = f2bf(od*c + e*sn);
  }
  u16* dst = isk ? (KAout + (size_t)(PAST_ + s)*DIM + tid*6)
                 : (Qout  + (size_t)s*DIM + tid*6);
  #pragma unroll
  for (int t=0;t<6;t++) dst[t] = ov[t];
}

// ---------------- flash attention (r1 core verbatim + kv-split partials) ----------------
// block = (q-tile 64, head, kv-half). 4 waves x 16 q-rows. KVB=64.
// Identical dataflow to round 1's PASSING kernel; only change: kv range per z
// and unnormalized (o, m, l) output for merge_attn.
__global__ __launch_bounds__(256, 3) void attn(
  const u16* __restrict__ Qf, const u16* __restrict__ KA,
  const u16* __restrict__ VA, u16* __restrict__ OP, float* __restrict__ ML)
{
  __shared__ __align__(16) u16 Ks[64*128];   // [kv][d], XOR-swizzled rows
  __shared__ __align__(16) u16 Vt[128*64];   // [d][kv] transposed, XOR-swizzled
  __shared__ __align__(16) u16 Ps[4][16*80]; // per-wave P, row stride 80
  int h = blockIdx.y, qt = blockIdx.x, z = blockIdx.z;
  int tid = threadIdx.x, lane = tid & 63, w = tid >> 6;
  int qrow0 = qt*64 + w*16;
  int kvbeg = z ? 6656 : 0;
  int kvend = z ? LPAD : 6656;
  short8 qa[4];
  {
    const u16* qb = Qf + (size_t)(qrow0 + (lane&15))*DIM + h*HD + (lane>>4)*8;
    #pragma unroll
    for (int kt=0;kt<4;kt++) qa[kt] = *(const short8*)(qb + kt*32);
  }
  f32x4 o[8];
  #pragma unroll
  for (int dt=0;dt<8;dt++) o[dt] = (f32x4){0.f,0.f,0.f,0.f};
  float m[4] = {-1e30f,-1e30f,-1e30f,-1e30f};
  float l[4] = {0.f,0.f,0.f,0.f};
  const float SC = 0.08838834764831845f * 1.4426950408889634f; // 1/sqrt(128) * log2(e)

  for (int kv0 = kvbeg; kv0 < kvend; kv0 += 64){
    // --- stage K via global_load_lds, source pre-swizzled ---
    #pragma unroll
    for (int p=0;p<4;p++){
      int e = w*2048 + p*512 + lane*8;
      int r = e >> 7;
      int bcol = (e & 127) << 1;             // byte col within 256B row
      int sb = bcol ^ ((r & 7) << 4);
      gload_lds16(KA + (size_t)(kv0 + r)*DIM + h*HD + (sb>>1),
                  (char*)Ks + w*4096 + p*1024);
    }
    // --- stage V transposed via registers ---
    {
      int c0 = (tid >> 4) << 3;   // d group 0..120
      int r0 = (tid & 15) << 2;   // kv group 0..60
      const u16* vs = VA + (size_t)(kv0 + r0)*DIM + h*HD + c0;
      short8 v0 = *(const short8*)(vs);
      short8 v1 = *(const short8*)(vs + DIM);
      short8 v2 = *(const short8*)(vs + 2*DIM);
      short8 v3 = *(const short8*)(vs + 3*DIM);
      #pragma unroll
      for (int j=0;j<8;j++){
        int d = c0 + j;
        int off = d*128 + ((r0*2) ^ ((d & 7) << 4));
        us4 pk; pk[0]=(u16)v0[j]; pk[1]=(u16)v1[j]; pk[2]=(u16)v2[j]; pk[3]=(u16)v3[j];
        *(us4*)((char*)Vt + off) = pk;
      }
    }
    __syncthreads();
    // --- QK^T ---
    f32x4 s4[4];
    #pragma unroll
    for (int ct=0;ct<4;ct++) s4[ct] = (f32x4){0.f,0.f,0.f,0.f};
    #pragma unroll
    for (int ct=0;ct<4;ct++){
      int row = ct*16 + (lane&15);
      int rbyte = row*256, sw = (row & 7) << 4;
      #pragma unroll
      for (int kt=0;kt<4;kt++){
        int b = (kt*64 + ((lane>>4)<<4)) ^ sw;
        short8 kb = *(const short8*)((const char*)Ks + rbyte + b);
        s4[ct] = __builtin_amdgcn_mfma_f32_16x16x32_bf16(qa[kt], kb, s4[ct], 0,0,0);
      }
    }
    // --- online softmax (exp2 domain) ---
    float xv[4][4];
    #pragma unroll
    for (int ct=0;ct<4;ct++)
      #pragma unroll
      for (int j=0;j<4;j++) xv[ct][j] = s4[ct][j] * SC;
    if (kv0 + 64 > LTOT){
      #pragma unroll
      for (int ct=0;ct<4;ct++){
        int col = kv0 + ct*16 + (lane&15);
        if (col >= LTOT){
          #pragma unroll
          for (int j=0;j<4;j++) xv[ct][j] = -1e30f;
        }
      }
    }
    float al[4];
    #pragma unroll
    for (int j=0;j<4;j++){
      float rm = fmaxf(fmaxf(xv[0][j],xv[1][j]), fmaxf(xv[2][j],xv[3][j]));
      rm = fmaxf(rm, __shfl_xor(rm, 1));
      rm = fmaxf(rm, __shfl_xor(rm, 2));
      rm = fmaxf(rm, __shfl_xor(rm, 4));
      rm = fmaxf(rm, __shfl_xor(rm, 8));
      float mn = fmaxf(m[j], rm);
      al[j] = exp2f(m[j] - mn);
      m[j] = mn;
    }
    #pragma unroll
    for (int ct=0;ct<4;ct++)
      #pragma unroll
      for (int j=0;j<4;j++) xv[ct][j] = exp2f(xv[ct][j] - m[j]);
    #pragma unroll
    for (int j=0;j<4;j++){
      float rs = xv[0][j]+xv[1][j]+xv[2][j]+xv[3][j];
      rs += __shfl_xor(rs, 1); rs += __shfl_xor(rs, 2);
      rs += __shfl_xor(rs, 4); rs += __shfl_xor(rs, 8);
      l[j] = l[j]*al[j] + rs;
    }
    #pragma unroll
    for (int dt=0;dt<8;dt++){
      f32x4 t = o[dt];
      t[0]*=al[0]; t[1]*=al[1]; t[2]*=al[2]; t[3]*=al[3];
      o[dt] = t;
    }
    // --- P -> LDS (bf16) -> A-frags ---
    u16* pw = &Ps[w][0];
    #pragma unroll
    for (int ct=0;ct<4;ct++)
      #pragma unroll
      for (int j=0;j<4;j++)
        pw[((lane>>4)*4 + j)*80 + ct*16 + (lane&15)] = f2bf(xv[ct][j]);
    short8 pa[2];
    #pragma unroll
    for (int kh=0;kh<2;kh++)
      pa[kh] = *(const short8*)&pw[(lane&15)*80 + kh*32 + (lane>>4)*8];
    // --- PV ---
    #pragma unroll
    for (int dt=0;dt<8;dt++){
      int row = dt*16 + (lane&15);
      int rbyte = row*128, sw = (row & 7) << 4;
      #pragma unroll
      for (int kh=0;kh<2;kh++){
        int b = (kh*64 + ((lane>>4)<<4)) ^ sw;
        short8 vb = *(const short8*)((const char*)Vt + rbyte + b);
        o[dt] = __builtin_amdgcn_mfma_f32_16x16x32_bf16(pa[kh], vb, o[dt], 0,0,0);
      }
    }
    __syncthreads();
  }
  // --- store UNNORMALIZED partial (bf16) + (m,l) per q-row ---
  #pragma unroll
  for (int dt=0;dt<8;dt++){
    #pragma unroll
    for (int j=0;j<4;j++){
      int row = qrow0 + (lane>>4)*4 + j;
      OP[((size_t)(z*SPAD + row)*NH + h)*HD + dt*16 + (lane&15)] = f2bf(o[dt][j]);
    }
  }
  if ((lane & 15) == 0){
    #pragma unroll
    for (int j=0;j<4;j++){
      int row = qrow0 + (lane>>4)*4 + j;
      size_t mb = ((size_t)(z*SPAD + row)*NH + h)*2;
      ML[mb] = m[j]; ML[mb+1] = l[j];
    }
  }
}

// ---------------- merge kv-split partials ----------------
__global__ void merge_attn(const u16* __restrict__ OP, const float* __restrict__ ML,
                           u16* __restrict__ AB)
{
  int s = blockIdx.x, h = blockIdx.y, d = threadIdx.x;
  size_t i1 = ((size_t)s*NH + h)*2;
  size_t i2 = ((size_t)(SPAD + s)*NH + h)*2;
  float m1 = ML[i1], l1 = ML[i1+1];
  float m2 = ML[i2], l2 = ML[i2+1];
  float M = fmaxf(m1, m2);
  float e1 = exp2f(m1 - M), e2 = exp2f(m2 - M);
  float den = 1.0f / (l1*e1 + l2*e2);
  float o1 = bf2f(OP[((size_t)s*NH + h)*HD + d]);
  float o2 = bf2f(OP[((size_t)(SPAD + s)*NH + h)*HD + d]);
  AB[(size_t)s*DIM + h*HD + d] = f2bf((o1*e1 + o2*e2) * den);
}

// ---------------- launch ----------------
extern "C" void kernel_launch(void* const* d_in, const int* in_sizes, int n_in,
                              void* d_out, int out_size, void* d_ws, size_t ws_size,
                              hipStream_t stream) {
  (void)in_sizes; (void)n_in; (void)out_size; (void)ws_size;
  const float* x    = (const float*)d_in[0];
  const float* freqs= (const float*)d_in[1];
  const float* ck   = (const float*)d_in[2];
  const float* cv   = (const float*)d_in[3];
  const float* Wq   = (const float*)d_in[4];
  const float* bq   = (const float*)d_in[5];
  const float* Wk   = (const float*)d_in[6];
  const float* bk   = (const float*)d_in[7];
  const float* Wv   = (const float*)d_in[8];
  const float* bv   = (const float*)d_in[9];
  const float* Wo   = (const float*)d_in[10];
  const float* bo   = (const float*)d_in[11];
  const float* gq   = (const float*)d_in[12];
  const float* gk   = (const float*)d_in[13];
  const int*   cs   = (const int*)d_in[14];
  float* out = (float*)d_out;
  char* ws = (char*)d_ws;

  // layout: AB, Wb3, QL, KA, VA, [Wb0, Wb1, Wb2, KL]  (bracketed region reused
  // during attn for OP (bf16 partials) + ML (f32 m,l))
  u16* AB  = (u16*)(ws);                      // 8,257,536
  u16* Wb3 = (u16*)(ws + 8257536);            // 4,718,592
  u16* QL  = (u16*)(ws + 12976128);           // 8,257,536
  u16* KA  = (u16*)(ws + 21233664);           // 40,697,856
  u16* VA  = (u16*)(ws + 61931520);           // 40,697,856
  u16* Wb0 = (u16*)(ws + 102629376);
  u16* Wb1 = (u16*)(ws + 107347968);
  u16* Wb2 = (u16*)(ws + 112066560);
  u16* KL  = (u16*)(ws + 116785152);          // ends 124,895,232
  u16*   OP = (u16*)(ws + 102629376);         // 16,515,072 (2 x 2688 x 12 x 128 bf16)
  float* ML = (float*)(ws + 119144448);       // 516,096

  k_cvt<<<2304, 256, 0, stream>>>(Wq, Wb0, 589824);
  k_cvt<<<2304, 256, 0, stream>>>(Wk, Wb1, 589824);
  k_cvt<<<2304, 256, 0, stream>>>(Wv, Wb2, 589824);
  k_cvt<<<2304, 256, 0, stream>>>(Wo, Wb3, 589824);
  k_prep_x<<<4032, 256, 0, stream>>>(x, AB);
  k_prep_cache<<<15912, 256, 0, stream>>>(ck, KA, 4073472);
  k_prep_cache<<<15912, 256, 0, stream>>>(cv, VA, 4073472);
  k_zero<<<72, 256, 0, stream>>>(QL + (size_t)SQ_*DIM, 18432);

  gemm_qkv<<<dim3(21,36), 256, 0, stream>>>(AB, Wb0, Wb1, Wb2, bq, bk, bv, QL, KL, VA);
  norm_rope<<<dim3(2640,2), 256, 0, stream>>>(QL, KL, freqs, gq, gk, cs, QL, KA);
  attn<<<dim3(42,12,2), 256, 0, stream>>>(QL, KA, VA, OP, ML);
  merge_attn<<<dim3(2640,12), 128, 0, stream>>>(OP, ML, AB);
  gemm_out<<<dim3(21,12), 256, 0, stream>>>(AB, Wb3, bo, out);
}